// Round 2
// baseline (285.034 us; speedup 1.0000x reference)
//
#include <hip/hip_runtime.h>
#include <hip/hip_bf16.h>

#define EDIM 256
#define HEADS 8
#define INV_SQRT_D 0.17677669529663688f   // 1/sqrt(32)
#define FXSCALE 1099511627776.0f          // 2^40 fixed-point scale

// Plan A ws layout:
//   float idx [0 .. 4095]   W[16][256]: rows 0..7 = (q_h^T Wk_h)/sqrt(D), rows 8..15 = u_h^T Wv_h
//   float idx [4096..4103]  qb[h] = (q_h . bk_h)/sqrt(D)
//   float idx [4104..4111]  ub[h] = u_h . bv_h
//   float idx [4112]        c = w_lin . b_out + b_lin
//   byte 32768 ..           ZM[G][16] int64 fixed-point: slot 2h = Z, 2h+1 = M
#define WS_W   0
#define WS_QB  4096
#define WS_UB  4104
#define WS_C   4112
#define ZM_BYTE_OFF 32768

// ---- shared device helper: 16 dots of length 256 reduced across the wave ----
// Input: W[16] (this lane's 4 elems of each folded row), xv (this lane's 4
// elems of x). Output: this lane's reduced value; lane l (l&15) ends up
// holding value index jv = bitrev4(l&15) summed over all 64 lanes.
__device__ __forceinline__ float dot16_reduce(const float4 (&W)[16],
                                              const float4 xv, const int lane) {
  float p[16];
#pragma unroll
  for (int j = 0; j < 16; ++j)
    p[j] = W[j].x * xv.x + W[j].y * xv.y + W[j].z * xv.z + W[j].w * xv.w;
#pragma unroll
  for (int j = 0; j < 8; ++j) {
    float send = (lane & 1) ? p[j] : p[j + 8];
    float keep = (lane & 1) ? p[j + 8] : p[j];
    p[j] = keep + __shfl_xor(send, 1, 64);
  }
#pragma unroll
  for (int j = 0; j < 4; ++j) {
    float send = (lane & 2) ? p[j] : p[j + 4];
    float keep = (lane & 2) ? p[j + 4] : p[j];
    p[j] = keep + __shfl_xor(send, 2, 64);
  }
#pragma unroll
  for (int j = 0; j < 2; ++j) {
    float send = (lane & 4) ? p[j] : p[j + 2];
    float keep = (lane & 4) ? p[j + 2] : p[j];
    p[j] = keep + __shfl_xor(send, 4, 64);
  }
  {
    float send = (lane & 8) ? p[0] : p[1];
    float keep = (lane & 8) ? p[1] : p[0];
    p[0] = keep + __shfl_xor(send, 8, 64);
  }
  p[0] += __shfl_xor(p[0], 16, 64);
  p[0] += __shfl_xor(p[0], 32, 64);
  return p[0];
}

__device__ __forceinline__ int bitrev4(const int l4) {
  return ((l4 & 1) << 3) | ((l4 & 2) << 1) | ((l4 & 4) >> 1) | ((l4 & 8) >> 3);
}

// ---------------- Plan A, kernel 1: all weight folding + ZM zeroing ----------
__global__ __launch_bounds__(256) void prep_all(
    const float* __restrict__ query, const float* __restrict__ w_in,
    const float* __restrict__ b_in, const float* __restrict__ w_out,
    const float* __restrict__ b_out, const float* __restrict__ w_lin,
    const float* __restrict__ b_lin, float* __restrict__ ws,
    unsigned long long* __restrict__ zm, int G) {
  __shared__ float querys[EDIM], wls[EDIM], qs[EDIM], us[EDIM];
  const int t = threadIdx.x;
  for (int i = t; i < G * 16; i += 256) zm[i] = 0ull;   // zero accumulators
  querys[t] = query[t];
  wls[t] = w_lin[t];
  __syncthreads();
  {  // q[t] = query . Wq_row_t + bq[t]
    float acc = 0.f;
    const float4* wr = (const float4*)(w_in + (size_t)t * EDIM);
#pragma unroll 4
    for (int f4 = 0; f4 < EDIM / 4; ++f4) {
      float4 wv = wr[f4];
      int f = f4 * 4;
      acc += wv.x * querys[f] + wv.y * querys[f + 1] + wv.z * querys[f + 2] + wv.w * querys[f + 3];
    }
    qs[t] = acc + b_in[t];
  }
  {  // u[t] = sum_f w_lin[f] * w_out[f,t]
    float acc = 0.f;
    for (int f = 0; f < EDIM; ++f) acc += wls[f] * w_out[(size_t)f * EDIM + t];
    us[t] = acc;
  }
  __syncthreads();
  // fold: W row j (<8) = (q_h^T Wk_h)/sqrt(D); row 8+j = u_h^T Wv_h
  for (int j = 0; j < 8; ++j) {
    float a = 0.f;
#pragma unroll 8
    for (int d = 0; d < 32; ++d)
      a += qs[j * 32 + d] * w_in[(size_t)(EDIM + j * 32 + d) * EDIM + t];
    ws[WS_W + j * EDIM + t] = a * INV_SQRT_D;
  }
  for (int j = 0; j < 8; ++j) {
    float a = 0.f;
#pragma unroll 8
    for (int d = 0; d < 32; ++d)
      a += us[j * 32 + d] * w_in[(size_t)(2 * EDIM + j * 32 + d) * EDIM + t];
    ws[WS_W + (8 + j) * EDIM + t] = a;
  }
  if (t < HEADS) {
    float qb = 0.f, ub = 0.f;
#pragma unroll 4
    for (int d = 0; d < 32; ++d) {
      qb += qs[t * 32 + d] * b_in[EDIM + t * 32 + d];
      ub += us[t * 32 + d] * b_in[2 * EDIM + t * 32 + d];
    }
    ws[WS_QB + t] = qb * INV_SQRT_D;
    ws[WS_UB + t] = ub;
  }
  if (t == 0) {
    float c = b_lin[0];
    for (int f = 0; f < EDIM; ++f) c += wls[f] * b_out[f];
    ws[WS_C] = c;
  }
}

// ---------------- Plan A, kernel 2: per-item dots + int64 fixed-point atomics
__global__ __launch_bounds__(256, 4) void main_items(
    const float* __restrict__ x, const int* __restrict__ gid,
    const float* __restrict__ ws, unsigned long long* __restrict__ zm,
    int n_items) {
  const int lane = threadIdx.x & 63;
  const int wid = (int)((blockIdx.x * blockDim.x + threadIdx.x) >> 6);
  const int nw = (int)((gridDim.x * blockDim.x) >> 6);

  float4 W[16];
#pragma unroll
  for (int j = 0; j < 16; ++j)
    W[j] = *(const float4*)(ws + WS_W + j * EDIM + lane * 4);

  const int jv = bitrev4(lane & 15);
  const int h = jv & 7;
  const int isw = (jv >> 3) & 1;   // 0: score (Z) slot, 1: value (M) slot
  const float bias_s = ws[WS_QB + h];
  const float bias_w = ws[WS_UB + h];

  for (int i = wid; i < n_items; i += nw) {
    const int g = gid[i];
    const float4 xv = *(const float4*)(x + (size_t)i * EDIM + lane * 4);
    const float p0 = dot16_reduce(W, xv, lane);
    const float tpair = __shfl_xor(p0, 1, 64);   // partner slot (same h, other isw)
    const float sv = (isw ? tpair : p0) + bias_s;
    const float wv = (isw ? p0 : tpair) + bias_w;
    const float e = __expf(sv);
    const float val = isw ? e * wv : e;
    if (lane < 16) {
      const long long qv = llrintf(val * FXSCALE);   // exact integer accumulation
      atomicAdd(zm + ((size_t)g * 16 + h * 2 + isw), (unsigned long long)qv);
    }
  }
}

// ---------------- Plan A, kernel 3: out[g] = c + sum_h M/Z ------------------
__global__ __launch_bounds__(256) void finalize(
    const long long* __restrict__ zm, const float* __restrict__ ws,
    float* __restrict__ out, int G) {
  const int g = blockIdx.x * blockDim.x + threadIdx.x;
  if (g >= G) return;
  double acc = (double)ws[WS_C];
  const long long* row = zm + (size_t)g * 16;
#pragma unroll
  for (int hh = 0; hh < 8; ++hh)
    acc += (double)row[hh * 2 + 1] / (double)row[hh * 2];   // 2^40 scales cancel
  out[g] = (float)acc;
}

// ---------------- Plan B (ws too small): one block per group, no scratch ----
__global__ __launch_bounds__(256) void group_scan(
    const float* __restrict__ x, const int* __restrict__ gid,
    const float* __restrict__ query, const float* __restrict__ w_in,
    const float* __restrict__ b_in, const float* __restrict__ w_out,
    const float* __restrict__ b_out, const float* __restrict__ w_lin,
    const float* __restrict__ b_lin, float* __restrict__ out, int n_items) {
  const int g = blockIdx.x;
  const int t = threadIdx.x;
  __shared__ float Wl[16 * EDIM];
  __shared__ float querys[EDIM], wls[EDIM], qs[EDIM], us[EDIM];
  __shared__ float qbias[8], ubias[8], csh;
  __shared__ float part[4][16], sums[16];

  querys[t] = query[t];
  wls[t] = w_lin[t];
  __syncthreads();
  {
    float acc = 0.f;
    const float4* wr = (const float4*)(w_in + (size_t)t * EDIM);
    for (int f4 = 0; f4 < EDIM / 4; ++f4) {
      float4 wv = wr[f4];
      int f = f4 * 4;
      acc += wv.x * querys[f] + wv.y * querys[f + 1] + wv.z * querys[f + 2] + wv.w * querys[f + 3];
    }
    qs[t] = acc + b_in[t];
  }
  {
    float acc = 0.f;
    for (int f = 0; f < EDIM; ++f) acc += wls[f] * w_out[(size_t)f * EDIM + t];
    us[t] = acc;
  }
  __syncthreads();
  for (int j = 0; j < 8; ++j) {
    float a = 0.f;
    for (int d = 0; d < 32; ++d)
      a += qs[j * 32 + d] * w_in[(size_t)(EDIM + j * 32 + d) * EDIM + t];
    Wl[j * EDIM + t] = a * INV_SQRT_D;
  }
  for (int j = 0; j < 8; ++j) {
    float a = 0.f;
    for (int d = 0; d < 32; ++d)
      a += us[j * 32 + d] * w_in[(size_t)(2 * EDIM + j * 32 + d) * EDIM + t];
    Wl[(8 + j) * EDIM + t] = a;
  }
  if (t < HEADS) {
    float qb = 0.f, ub = 0.f;
    for (int d = 0; d < 32; ++d) {
      qb += qs[t * 32 + d] * b_in[EDIM + t * 32 + d];
      ub += us[t * 32 + d] * b_in[2 * EDIM + t * 32 + d];
    }
    qbias[t] = qb * INV_SQRT_D;
    ubias[t] = ub;
  }
  if (t == 0) {
    float c = b_lin[0];
    for (int f = 0; f < EDIM; ++f) c += wls[f] * b_out[f];
    csh = c;
  }
  __syncthreads();

  const int lane = t & 63;
  const int wave = t >> 6;
  float4 W[16];
#pragma unroll
  for (int j = 0; j < 16; ++j)
    W[j] = *(const float4*)(Wl + j * EDIM + lane * 4);
  const int jv = bitrev4(lane & 15);
  const int h = jv & 7;
  const int isw = (jv >> 3) & 1;
  const float bias_s = qbias[h];
  const float bias_w = ubias[h];

  float accv = 0.f;
  const int nchunk = (n_items + 63) >> 6;
  for (int c = wave; c < nchunk; c += 4) {      // fixed chunk->wave map
    const int i0 = c << 6;
    const int ii = i0 + lane;
    const int gi = (ii < n_items) ? gid[ii] : -1;
    unsigned long long m = __ballot(gi == g);
    while (m) {                                  // ascending item order: deterministic
      const int b = __ffsll(m) - 1;
      m &= m - 1;
      const int i = i0 + b;
      const float4 xv = *(const float4*)(x + (size_t)i * EDIM + lane * 4);
      const float p0 = dot16_reduce(W, xv, lane);
      const float tpair = __shfl_xor(p0, 1, 64);
      const float sv = (isw ? tpair : p0) + bias_s;
      const float wv = (isw ? p0 : tpair) + bias_w;
      const float e = __expf(sv);
      accv += isw ? e * wv : e;
    }
  }
  if (lane < 16) part[wave][h * 2 + isw] = accv;
  __syncthreads();
  if (t < 16) sums[t] = part[0][t] + part[1][t] + part[2][t] + part[3][t];
  __syncthreads();
  if (t == 0) {
    double acc = (double)csh;
    for (int hh = 0; hh < 8; ++hh)
      acc += (double)sums[2 * hh + 1] / (double)sums[2 * hh];
    out[g] = (float)acc;
  }
}

extern "C" void kernel_launch(void* const* d_in, const int* in_sizes, int n_in,
                              void* d_out, int out_size, void* d_ws, size_t ws_size,
                              hipStream_t stream) {
  const float* tree_preds = (const float*)d_in[0];
  const int* group_ids = (const int*)d_in[1];
  const float* query = (const float*)d_in[2];
  const float* w_in = (const float*)d_in[3];
  const float* b_in = (const float*)d_in[4];
  const float* w_out = (const float*)d_in[5];
  const float* b_out = (const float*)d_in[6];
  const float* w_lin = (const float*)d_in[7];
  const float* b_lin = (const float*)d_in[8];
  float* out = (float*)d_out;

  const int N = in_sizes[1];   // 131072
  const int G = out_size;      // 2048

  const size_t needA = (size_t)ZM_BYTE_OFF + (size_t)G * 16 * 8;
  if (ws_size >= needA) {
    float* ws = (float*)d_ws;
    unsigned long long* zm = (unsigned long long*)((char*)d_ws + ZM_BYTE_OFF);
    prep_all<<<1, 256, 0, stream>>>(query, w_in, b_in, w_out, b_out, w_lin, b_lin, ws, zm, G);
    main_items<<<1024, 256, 0, stream>>>(tree_preds, group_ids, ws, zm, N);
    finalize<<<(G + 255) / 256, 256, 0, stream>>>((const long long*)zm, ws, out, G);
  } else {
    group_scan<<<G, 256, 0, stream>>>(tree_preds, group_ids, query, w_in, b_in,
                                      w_out, b_out, w_lin, b_lin, out, N);
  }
}

// Round 3
// 221.210 us; speedup vs baseline: 1.2885x; 1.2885x over previous
//
#include <hip/hip_runtime.h>
#include <hip/hip_bf16.h>

#define EDIM 256
#define INV_SQRT_D 0.17677669529663688f   // 1/sqrt(32)
#define FXSCALE 1099511627776.0f          // 2^40 fixed-point scale

// ws layout:
//   float idx [4096..4103]  qb[h] = (q_h . bk_h)/sqrt(D)
//   float idx [4104..4111]  ub[h] = u_h . bv_h
//   float idx [4112]        c = w_lin . b_out + b_lin
//   float idx [4128..4383]  qs[256] (q vector)
//   float idx [4608..8703]  partial_u[16][256]
//   byte 36864..45055       Wb bf16[16][256]: rows 0..7 = (q_h^T Wk_h)/sqrt(D), 8..15 = u_h^T Wv_h
//   byte 65536..            ZM[G][16] int64 fixed-point: slot 2h = Z, 2h+1 = M
#define WS_QB   4096
#define WS_UB   4104
#define WS_C    4112
#define WS_QS   4128
#define WS_PU   4608
#define WB_BYTE_OFF 36864
#define ZM_BYTE_OFF 65536

typedef __attribute__((ext_vector_type(8))) short short8;
typedef __attribute__((ext_vector_type(4))) float f32x4;

__device__ __forceinline__ unsigned short f2bf(float f) {
  unsigned u = __float_as_uint(f);
  unsigned r = (u + 0x7fffu + ((u >> 16) & 1u)) >> 16;   // RNE truncate to bf16
  return (unsigned short)r;
}

// ---------------- zero the ZM accumulators ----------------------------------
__global__ __launch_bounds__(256) void zero_zm(unsigned long long* __restrict__ zm, int n) {
  const int i = blockIdx.x * 256 + threadIdx.x;
  const int stride = gridDim.x * 256;
  for (int k = i; k < n; k += stride) zm[k] = 0ull;
}

// ---------------- prep1: q rows (blocks 0..31), partial u (blocks 32..47) ---
__global__ __launch_bounds__(256) void prep1(
    const float* __restrict__ query, const float* __restrict__ w_in,
    const float* __restrict__ b_in, const float* __restrict__ w_out,
    const float* __restrict__ w_lin, float* __restrict__ ws) {
  const int b = blockIdx.x, t = threadIdx.x;
  if (b < 32) {
    // row r handled by a 32-lane half-wave; lane covers 8 feats
    const int r = b * 8 + (t >> 5);
    const int l = t & 31;
    const float4 q0 = *(const float4*)(query + l * 8);
    const float4 q1 = *(const float4*)(query + l * 8 + 4);
    const float4 w0 = *(const float4*)(w_in + (size_t)r * EDIM + l * 8);
    const float4 w1 = *(const float4*)(w_in + (size_t)r * EDIM + l * 8 + 4);
    float a = q0.x * w0.x + q0.y * w0.y + q0.z * w0.z + q0.w * w0.w
            + q1.x * w1.x + q1.y * w1.y + q1.z * w1.z + q1.w * w1.w;
    for (int m = 16; m >= 1; m >>= 1) a += __shfl_xor(a, m, 32);
    if (l == 0) ws[WS_QS + r] = a + b_in[r];
  } else {
    const int k = b - 32;   // 16-row slab of w_out
    float acc = 0.f;
#pragma unroll
    for (int f = 0; f < 16; ++f) {
      const int fr = k * 16 + f;
      acc += w_lin[fr] * w_out[(size_t)fr * EDIM + t];
    }
    ws[WS_PU + k * EDIM + t] = acc;
  }
}

// ---------------- prep2: fold into bf16 W rows + scalars --------------------
__global__ __launch_bounds__(256) void prep2(
    const float* __restrict__ w_in, const float* __restrict__ b_in,
    const float* __restrict__ b_out, const float* __restrict__ b_lin,
    const float* __restrict__ w_lin, float* __restrict__ ws,
    unsigned short* __restrict__ wb) {
  const int b = blockIdx.x, t = threadIdx.x;
  if (b < 8) {                       // score rows: (q_h^T Wk_h)/sqrt(D)
    __shared__ float qh[32];
    if (t < 32) qh[t] = ws[WS_QS + b * 32 + t];
    __syncthreads();
    float a = 0.f;
#pragma unroll 8
    for (int d = 0; d < 32; ++d)
      a += qh[d] * w_in[(size_t)(EDIM + b * 32 + d) * EDIM + t];
    wb[b * EDIM + t] = f2bf(a * INV_SQRT_D);
  } else if (b < 16) {               // value rows: u_h^T Wv_h
    const int j = b - 8;
    __shared__ float uh[32];
    if (t < 32) {
      float s = 0.f;
#pragma unroll
      for (int k = 0; k < 16; ++k) s += ws[WS_PU + k * EDIM + j * 32 + t];
      uh[t] = s;
    }
    __syncthreads();
    float a = 0.f;
#pragma unroll 8
    for (int d = 0; d < 32; ++d)
      a += uh[d] * w_in[(size_t)(2 * EDIM + j * 32 + d) * EDIM + t];
    wb[(8 + j) * EDIM + t] = f2bf(a);
  } else {                           // scalars qb, ub, c
    __shared__ float us[EDIM];
    float s = 0.f;
#pragma unroll
    for (int k = 0; k < 16; ++k) s += ws[WS_PU + k * EDIM + t];
    us[t] = s;
    __syncthreads();
    if (t < 8) {
      float qb = 0.f, ub = 0.f;
#pragma unroll 4
      for (int d = 0; d < 32; ++d) {
        qb += ws[WS_QS + t * 32 + d] * b_in[EDIM + t * 32 + d];
        ub += us[t * 32 + d] * b_in[2 * EDIM + t * 32 + d];
      }
      ws[WS_QB + t] = qb * INV_SQRT_D;
      ws[WS_UB + t] = ub;
    }
    if (t == 0) {
      float c = b_lin[0];
      for (int f = 0; f < EDIM; ++f) c += w_lin[f] * b_out[f];
      ws[WS_C] = c;
    }
  }
}

// ---------------- main: MFMA per 16-item tile + int64 atomics ---------------
#define LROW 260   // bf16 elems per LDS row (stride 520 B: conflict-free frag reads)
__global__ __launch_bounds__(256, 4) void main_mfma(
    const float* __restrict__ x, const int* __restrict__ gid,
    const float* __restrict__ ws, const unsigned short* __restrict__ wb,
    unsigned long long* __restrict__ zm, int n_items) {
  __shared__ unsigned short lds[4 * 16 * LROW];
  const int t = threadIdx.x;
  const int lane = t & 63, wave = t >> 6;
  unsigned short* my = lds + wave * 16 * LROW;
  const int wid = (int)(blockIdx.x * 4 + wave);
  const int nw = (int)(gridDim.x * 4);
  const int n = lane & 15, quad = lane >> 4;
  const int h = n & 7, isw = (n >> 3) & 1;   // n<8: Z slot (score), n>=8: M slot

  // B fragments: Wb row n, feats quad*8 + kc*32 .. +8
  short8 bfrag[8];
#pragma unroll
  for (int kc = 0; kc < 8; ++kc)
    bfrag[kc] = *(const short8*)(wb + n * EDIM + quad * 8 + kc * 32);

  const float qb = ws[WS_QB + h];
  const float ub = ws[WS_UB + h];

  const int ntiles = (n_items + 15) >> 4;
  for (int tile = wid; tile < ntiles; tile += nw) {
    const int base = tile << 4;
    const bool full = (base + 16 <= n_items);
    int4 g4;
    if (full) {
      g4 = *(const int4*)(gid + base + quad * 4);
#pragma unroll
      for (int i = 0; i < 16; ++i) {
        const float4 v = *(const float4*)(x + (size_t)(base + i) * EDIM + lane * 4);
        union { unsigned short s[4]; unsigned long long ll; } pk;
        pk.s[0] = f2bf(v.x); pk.s[1] = f2bf(v.y);
        pk.s[2] = f2bf(v.z); pk.s[3] = f2bf(v.w);
        *(unsigned long long*)(my + i * LROW + lane * 4) = pk.ll;
      }
    } else {                                   // tail tile (unused at N=131072)
      int gg[4];
      for (int r = 0; r < 4; ++r) {
        const int m = quad * 4 + r;
        gg[r] = (base + m < n_items) ? gid[base + m] : 0;
      }
      g4.x = gg[0]; g4.y = gg[1]; g4.z = gg[2]; g4.w = gg[3];
      for (int i = 0; i < 16; ++i) {
        union { unsigned short s[4]; unsigned long long ll; } pk;
        if (base + i < n_items) {
          const float4 v = *(const float4*)(x + (size_t)(base + i) * EDIM + lane * 4);
          pk.s[0] = f2bf(v.x); pk.s[1] = f2bf(v.y);
          pk.s[2] = f2bf(v.z); pk.s[3] = f2bf(v.w);
        } else pk.ll = 0ull;
        *(unsigned long long*)(my + i * LROW + lane * 4) = pk.ll;
      }
    }
    // A fragments from LDS (wave-private: compiler inserts lgkmcnt waits)
    f32x4 acc = {0.f, 0.f, 0.f, 0.f};
#pragma unroll
    for (int kc = 0; kc < 8; ++kc) {
      const short8 a = *(const short8*)(my + n * LROW + quad * 8 + kc * 32);
      acc = __builtin_amdgcn_mfma_f32_16x16x32_bf16(a, bfrag[kc], acc, 0, 0, 0);
    }
    // epilogue: C[m][n], m = quad*4 + r (item), n = slot
#pragma unroll
    for (int r = 0; r < 4; ++r) {
      const int m = quad * 4 + r;
      const float mine = acc[r];
      const float partner = __shfl_xor(mine, 8, 64);   // slot n^8, same item
      const float sv = (isw ? partner : mine) + qb;
      const float wv = (isw ? mine : partner) + ub;
      const float e = __expf(sv);
      const float val = isw ? e * wv : e;
      const int g = (r == 0) ? g4.x : (r == 1) ? g4.y : (r == 2) ? g4.z : g4.w;
      if (base + m < n_items) {
        const long long qv = llrintf(val * FXSCALE);
        atomicAdd(zm + ((size_t)g * 16 + h * 2 + isw), (unsigned long long)qv);
      }
    }
  }
}

// ---------------- finalize: out[g] = c + sum_h M/Z --------------------------
__global__ __launch_bounds__(256) void finalize(
    const long long* __restrict__ zm, const float* __restrict__ ws,
    float* __restrict__ out, int G) {
  const int g = blockIdx.x * blockDim.x + threadIdx.x;
  if (g >= G) return;
  double acc = (double)ws[WS_C];
  const long long* row = zm + (size_t)g * 16;
#pragma unroll
  for (int hh = 0; hh < 8; ++hh)
    acc += (double)row[hh * 2 + 1] / (double)row[hh * 2];   // 2^40 scales cancel
  out[g] = (float)acc;
}

// ---------------- Plan B (ws too small): one block per group, no scratch ----
__device__ __forceinline__ float dot16_reduce(const float4 (&W)[16],
                                              const float4 xv, const int lane) {
  float p[16];
#pragma unroll
  for (int j = 0; j < 16; ++j)
    p[j] = W[j].x * xv.x + W[j].y * xv.y + W[j].z * xv.z + W[j].w * xv.w;
#pragma unroll
  for (int j = 0; j < 8; ++j) {
    float send = (lane & 1) ? p[j] : p[j + 8];
    float keep = (lane & 1) ? p[j + 8] : p[j];
    p[j] = keep + __shfl_xor(send, 1, 64);
  }
#pragma unroll
  for (int j = 0; j < 4; ++j) {
    float send = (lane & 2) ? p[j] : p[j + 4];
    float keep = (lane & 2) ? p[j + 4] : p[j];
    p[j] = keep + __shfl_xor(send, 2, 64);
  }
#pragma unroll
  for (int j = 0; j < 2; ++j) {
    float send = (lane & 4) ? p[j] : p[j + 2];
    float keep = (lane & 4) ? p[j + 2] : p[j];
    p[j] = keep + __shfl_xor(send, 4, 64);
  }
  {
    float send = (lane & 8) ? p[0] : p[1];
    float keep = (lane & 8) ? p[1] : p[0];
    p[0] = keep + __shfl_xor(send, 8, 64);
  }
  p[0] += __shfl_xor(p[0], 16, 64);
  p[0] += __shfl_xor(p[0], 32, 64);
  return p[0];
}

__device__ __forceinline__ int bitrev4(const int l4) {
  return ((l4 & 1) << 3) | ((l4 & 2) << 1) | ((l4 & 4) >> 1) | ((l4 & 8) >> 3);
}

__global__ __launch_bounds__(256) void group_scan(
    const float* __restrict__ x, const int* __restrict__ gid,
    const float* __restrict__ query, const float* __restrict__ w_in,
    const float* __restrict__ b_in, const float* __restrict__ w_out,
    const float* __restrict__ b_out, const float* __restrict__ w_lin,
    const float* __restrict__ b_lin, float* __restrict__ out, int n_items) {
  const int g = blockIdx.x;
  const int t = threadIdx.x;
  __shared__ float Wl[16 * EDIM];
  __shared__ float querys[EDIM], wls[EDIM], qs[EDIM], us[EDIM];
  __shared__ float qbias[8], ubias[8], csh;
  __shared__ float part[4][16], sums[16];

  querys[t] = query[t];
  wls[t] = w_lin[t];
  __syncthreads();
  {
    float acc = 0.f;
    const float4* wr = (const float4*)(w_in + (size_t)t * EDIM);
    for (int f4 = 0; f4 < EDIM / 4; ++f4) {
      float4 wv = wr[f4];
      int f = f4 * 4;
      acc += wv.x * querys[f] + wv.y * querys[f + 1] + wv.z * querys[f + 2] + wv.w * querys[f + 3];
    }
    qs[t] = acc + b_in[t];
  }
  {
    float acc = 0.f;
    for (int f = 0; f < EDIM; ++f) acc += wls[f] * w_out[(size_t)f * EDIM + t];
    us[t] = acc;
  }
  __syncthreads();
  for (int j = 0; j < 8; ++j) {
    float a = 0.f;
    for (int d = 0; d < 32; ++d)
      a += qs[j * 32 + d] * w_in[(size_t)(EDIM + j * 32 + d) * EDIM + t];
    Wl[j * EDIM + t] = a * INV_SQRT_D;
  }
  for (int j = 0; j < 8; ++j) {
    float a = 0.f;
    for (int d = 0; d < 32; ++d)
      a += us[j * 32 + d] * w_in[(size_t)(2 * EDIM + j * 32 + d) * EDIM + t];
    Wl[(8 + j) * EDIM + t] = a;
  }
  if (t < 8) {
    float qb = 0.f, ub = 0.f;
    for (int d = 0; d < 32; ++d) {
      qb += qs[t * 32 + d] * b_in[EDIM + t * 32 + d];
      ub += us[t * 32 + d] * b_in[2 * EDIM + t * 32 + d];
    }
    qbias[t] = qb * INV_SQRT_D;
    ubias[t] = ub;
  }
  if (t == 0) {
    float c = b_lin[0];
    for (int f = 0; f < EDIM; ++f) c += wls[f] * b_out[f];
    csh = c;
  }
  __syncthreads();

  const int lane = t & 63;
  const int wave = t >> 6;
  float4 W[16];
#pragma unroll
  for (int j = 0; j < 16; ++j)
    W[j] = *(const float4*)(Wl + j * EDIM + lane * 4);
  const int jv = bitrev4(lane & 15);
  const int h = jv & 7;
  const int isw = (jv >> 3) & 1;
  const float bias_s = qbias[h];
  const float bias_w = ubias[h];

  float accv = 0.f;
  const int nchunk = (n_items + 63) >> 6;
  for (int c = wave; c < nchunk; c += 4) {
    const int i0 = c << 6;
    const int ii = i0 + lane;
    const int gi = (ii < n_items) ? gid[ii] : -1;
    unsigned long long mk = __ballot(gi == g);
    while (mk) {
      const int bpos = __ffsll(mk) - 1;
      mk &= mk - 1;
      const int i = i0 + bpos;
      const float4 xv = *(const float4*)(x + (size_t)i * EDIM + lane * 4);
      const float p0 = dot16_reduce(W, xv, lane);
      const float tpair = __shfl_xor(p0, 1, 64);
      const float sv = (isw ? tpair : p0) + bias_s;
      const float wv = (isw ? p0 : tpair) + bias_w;
      const float e = __expf(sv);
      accv += isw ? e * wv : e;
    }
  }
  if (lane < 16) part[wave][h * 2 + isw] = accv;
  __syncthreads();
  if (t < 16) sums[t] = part[0][t] + part[1][t] + part[2][t] + part[3][t];
  __syncthreads();
  if (t == 0) {
    double acc = (double)csh;
    for (int hh = 0; hh < 8; ++hh)
      acc += (double)sums[2 * hh + 1] / (double)sums[2 * hh];
    out[g] = (float)acc;
  }
}

extern "C" void kernel_launch(void* const* d_in, const int* in_sizes, int n_in,
                              void* d_out, int out_size, void* d_ws, size_t ws_size,
                              hipStream_t stream) {
  const float* tree_preds = (const float*)d_in[0];
  const int* group_ids = (const int*)d_in[1];
  const float* query = (const float*)d_in[2];
  const float* w_in = (const float*)d_in[3];
  const float* b_in = (const float*)d_in[4];
  const float* w_out = (const float*)d_in[5];
  const float* b_out = (const float*)d_in[6];
  const float* w_lin = (const float*)d_in[7];
  const float* b_lin = (const float*)d_in[8];
  float* out = (float*)d_out;

  const int N = in_sizes[1];   // 131072
  const int G = out_size;      // 2048

  const size_t needA = (size_t)ZM_BYTE_OFF + (size_t)G * 16 * 8;
  if (ws_size >= needA) {
    float* ws = (float*)d_ws;
    unsigned short* wb = (unsigned short*)((char*)d_ws + WB_BYTE_OFF);
    unsigned long long* zm = (unsigned long long*)((char*)d_ws + ZM_BYTE_OFF);
    zero_zm<<<64, 256, 0, stream>>>(zm, G * 16);
    prep1<<<48, 256, 0, stream>>>(query, w_in, b_in, w_out, w_lin, ws);
    prep2<<<17, 256, 0, stream>>>(w_in, b_in, b_out, b_lin, w_lin, ws, wb);
    main_mfma<<<1024, 256, 0, stream>>>(tree_preds, group_ids, ws, wb, zm, N);
    finalize<<<(G + 255) / 256, 256, 0, stream>>>((const long long*)zm, ws, out, G);
  } else {
    group_scan<<<G, 256, 0, stream>>>(tree_preds, group_ids, query, w_in, b_in,
                                      w_out, b_out, w_lin, b_lin, out, N);
  }
}

// Round 4
// 219.450 us; speedup vs baseline: 1.2989x; 1.0080x over previous
//
#include <hip/hip_runtime.h>
#include <hip/hip_bf16.h>

#define EDIM 256
#define INV_SQRT_D 0.17677669529663688f   // 1/sqrt(32)
#define FXSCALE 1099511627776.0f          // 2^40 fixed-point scale

// ws layout:
//   float idx [4096..4103]  qb[h] = (q_h . bk_h)/sqrt(D)
//   float idx [4104..4111]  ub[h] = u_h . bv_h
//   float idx [4112]        c = w_lin . b_out + b_lin
//   float idx [4128..4383]  qs[256] (q vector)
//   float idx [4608..8703]  partial_u[16][256]
//   byte 36864..45055       Wb bf16[16][256]: rows 0..7 = (q_h^T Wk_h)/sqrt(D), 8..15 = u_h^T Wv_h
//   byte 65536..            ZM[G][16] int64 fixed-point: slot 2h = Z, 2h+1 = M
#define WS_QB   4096
#define WS_UB   4104
#define WS_C    4112
#define WS_QS   4128
#define WS_PU   4608
#define WB_BYTE_OFF 36864
#define ZM_BYTE_OFF 65536

typedef __attribute__((ext_vector_type(8))) short short8;
typedef __attribute__((ext_vector_type(4))) float f32x4;

__device__ __forceinline__ unsigned short f2bf(float f) {
  unsigned u = __float_as_uint(f);
  unsigned r = (u + 0x7fffu + ((u >> 16) & 1u)) >> 16;   // RNE truncate to bf16
  return (unsigned short)r;
}

__device__ __forceinline__ unsigned int cvt_pk_bf16(float a, float b) {
  __hip_bfloat162 t = __float22bfloat162_rn(float2{a, b});  // v_cvt_pk_bf16_f32
  unsigned int u;
  __builtin_memcpy(&u, &t, 4);
  return u;
}

// ---------------- prep1: q rows (b<32), partial u (32<=b<48), zero ZM (b>=48)
__global__ __launch_bounds__(256) void prep1(
    const float* __restrict__ query, const float* __restrict__ w_in,
    const float* __restrict__ b_in, const float* __restrict__ w_out,
    const float* __restrict__ w_lin, float* __restrict__ ws,
    unsigned long long* __restrict__ zm, int nzm) {
  const int b = blockIdx.x, t = threadIdx.x;
  if (b < 32) {
    // row r handled by a 32-lane half-wave; lane covers 8 feats
    const int r = b * 8 + (t >> 5);
    const int l = t & 31;
    const float4 q0 = *(const float4*)(query + l * 8);
    const float4 q1 = *(const float4*)(query + l * 8 + 4);
    const float4 w0 = *(const float4*)(w_in + (size_t)r * EDIM + l * 8);
    const float4 w1 = *(const float4*)(w_in + (size_t)r * EDIM + l * 8 + 4);
    float a = q0.x * w0.x + q0.y * w0.y + q0.z * w0.z + q0.w * w0.w
            + q1.x * w1.x + q1.y * w1.y + q1.z * w1.z + q1.w * w1.w;
    for (int m = 16; m >= 1; m >>= 1) a += __shfl_xor(a, m, 32);
    if (l == 0) ws[WS_QS + r] = a + b_in[r];
  } else if (b < 48) {
    const int k = b - 32;   // 16-row slab of w_out
    float acc = 0.f;
#pragma unroll
    for (int f = 0; f < 16; ++f) {
      const int fr = k * 16 + f;
      acc += w_lin[fr] * w_out[(size_t)fr * EDIM + t];
    }
    ws[WS_PU + k * EDIM + t] = acc;
  } else {
    for (int k = (b - 48) * 256 + t; k < nzm; k += 16 * 256) zm[k] = 0ull;
  }
}

// ---------------- prep2: fold into bf16 W rows + scalars --------------------
__global__ __launch_bounds__(256) void prep2(
    const float* __restrict__ w_in, const float* __restrict__ b_in,
    const float* __restrict__ b_out, const float* __restrict__ b_lin,
    const float* __restrict__ w_lin, float* __restrict__ ws,
    unsigned short* __restrict__ wb) {
  const int b = blockIdx.x, t = threadIdx.x;
  if (b < 8) {                       // score rows: (q_h^T Wk_h)/sqrt(D)
    __shared__ float qh[32];
    if (t < 32) qh[t] = ws[WS_QS + b * 32 + t];
    __syncthreads();
    float a = 0.f;
#pragma unroll 8
    for (int d = 0; d < 32; ++d)
      a += qh[d] * w_in[(size_t)(EDIM + b * 32 + d) * EDIM + t];
    wb[b * EDIM + t] = f2bf(a * INV_SQRT_D);
  } else if (b < 16) {               // value rows: u_h^T Wv_h
    const int j = b - 8;
    __shared__ float uh[32];
    if (t < 32) {
      float s = 0.f;
#pragma unroll
      for (int k = 0; k < 16; ++k) s += ws[WS_PU + k * EDIM + j * 32 + t];
      uh[t] = s;
    }
    __syncthreads();
    float a = 0.f;
#pragma unroll 8
    for (int d = 0; d < 32; ++d)
      a += uh[d] * w_in[(size_t)(2 * EDIM + j * 32 + d) * EDIM + t];
    wb[(8 + j) * EDIM + t] = f2bf(a);
  } else {                           // scalars qb, ub, c
    __shared__ float us[EDIM];
    float s = 0.f;
#pragma unroll
    for (int k = 0; k < 16; ++k) s += ws[WS_PU + k * EDIM + t];
    us[t] = s;
    __syncthreads();
    if (t < 8) {
      float qb = 0.f, ub = 0.f;
#pragma unroll 4
      for (int d = 0; d < 32; ++d) {
        qb += ws[WS_QS + t * 32 + d] * b_in[EDIM + t * 32 + d];
        ub += us[t * 32 + d] * b_in[2 * EDIM + t * 32 + d];
      }
      ws[WS_QB + t] = qb * INV_SQRT_D;
      ws[WS_UB + t] = ub;
    }
    if (t == 0) {
      float c = b_lin[0];
      for (int f = 0; f < EDIM; ++f) c += w_lin[f] * b_out[f];
      ws[WS_C] = c;
    }
  }
}

// ---------------- main: direct-fragment MFMA per 16-item tile, no LDS -------
// A-fragment layout for mfma_f32_16x16x32_bf16: lane (n = lane&15, quad =
// lane>>4) holds A[m=n][k=quad*8+j], j=0..7. We load exactly that from x:
// item base+n, feats quad*8 + kc*32 .. +8 (32 B/lane; the wave covers
// 16 items x 128 B contiguous per kc step -> full line utilization).
__global__ __launch_bounds__(256, 4) void main_mfma(
    const float* __restrict__ x, const int* __restrict__ gid,
    const float* __restrict__ ws, const unsigned short* __restrict__ wb,
    unsigned long long* __restrict__ zm, int n_items) {
  const int t = threadIdx.x;
  const int lane = t & 63;
  const int n = lane & 15, quad = lane >> 4;
  const int h = n & 7, isw = (n >> 3) & 1;   // n<8: Z (score) slot, n>=8: M slot

  // B fragments: Wb row n (slot), feats quad*8 + kc*32 .. +8
  short8 bfrag[8];
#pragma unroll
  for (int kc = 0; kc < 8; ++kc)
    bfrag[kc] = *(const short8*)(wb + n * EDIM + quad * 8 + kc * 32);

  const float qb = ws[WS_QB + h];
  const float ub = ws[WS_UB + h];

  const int wid = (int)(blockIdx.x * (blockDim.x >> 6) + (t >> 6));
  const int nw = (int)(gridDim.x * (blockDim.x >> 6));
  const int ntiles = (n_items + 15) >> 4;

  for (int tile = wid; tile < ntiles; tile += nw) {
    const int base = tile << 4;
    const float* rowp = x + (size_t)(base + n) * EDIM + quad * 8;
    f32x4 acc = {0.f, 0.f, 0.f, 0.f};
    int4 g4;
    if (base + 16 <= n_items) {                    // full tile (hot path)
      g4 = *(const int4*)(gid + base + quad * 4);
#pragma unroll
      for (int kc = 0; kc < 8; ++kc) {
        const float4 v0 = *(const float4*)(rowp + kc * 32);
        const float4 v1 = *(const float4*)(rowp + kc * 32 + 4);
        union { short8 s; unsigned int u[4]; } a;
        a.u[0] = cvt_pk_bf16(v0.x, v0.y);
        a.u[1] = cvt_pk_bf16(v0.z, v0.w);
        a.u[2] = cvt_pk_bf16(v1.x, v1.y);
        a.u[3] = cvt_pk_bf16(v1.z, v1.w);
        acc = __builtin_amdgcn_mfma_f32_16x16x32_bf16(a.s, bfrag[kc], acc, 0, 0, 0);
      }
    } else {                                       // tail tile (unused at N=131072)
      int gg[4];
#pragma unroll
      for (int r = 0; r < 4; ++r)
        gg[r] = (base + quad * 4 + r < n_items) ? gid[base + quad * 4 + r] : 0;
      g4.x = gg[0]; g4.y = gg[1]; g4.z = gg[2]; g4.w = gg[3];
      const bool live = (base + n < n_items);
#pragma unroll
      for (int kc = 0; kc < 8; ++kc) {
        float4 v0 = {0.f, 0.f, 0.f, 0.f}, v1 = {0.f, 0.f, 0.f, 0.f};
        if (live) {
          v0 = *(const float4*)(rowp + kc * 32);
          v1 = *(const float4*)(rowp + kc * 32 + 4);
        }
        union { short8 s; unsigned int u[4]; } a;
        a.u[0] = cvt_pk_bf16(v0.x, v0.y);
        a.u[1] = cvt_pk_bf16(v0.z, v0.w);
        a.u[2] = cvt_pk_bf16(v1.x, v1.y);
        a.u[3] = cvt_pk_bf16(v1.z, v1.w);
        acc = __builtin_amdgcn_mfma_f32_16x16x32_bf16(a.s, bfrag[kc], acc, 0, 0, 0);
      }
    }
    // epilogue: C[m][n] with m = quad*4 + r (item), n = slot
#pragma unroll
    for (int r = 0; r < 4; ++r) {
      const float mine = acc[r];
      const float partner = __shfl_xor(mine, 8, 64);   // slot n^8, same item
      const float sv = (isw ? partner : mine) + qb;
      const float wv = (isw ? mine : partner) + ub;
      const float e = __expf(sv);
      const float val = isw ? e * wv : e;
      const int g = (r == 0) ? g4.x : (r == 1) ? g4.y : (r == 2) ? g4.z : g4.w;
      if (base + quad * 4 + r < n_items) {
        const long long qv = llrintf(val * FXSCALE);   // exact integer accumulation
        atomicAdd(zm + ((size_t)g * 16 + h * 2 + isw), (unsigned long long)qv);
      }
    }
  }
}

// ---------------- finalize: out[g] = c + sum_h M/Z --------------------------
__global__ __launch_bounds__(256) void finalize(
    const long long* __restrict__ zm, const float* __restrict__ ws,
    float* __restrict__ out, int G) {
  const int g = blockIdx.x * blockDim.x + threadIdx.x;
  if (g >= G) return;
  double acc = (double)ws[WS_C];
  const long long* row = zm + (size_t)g * 16;
#pragma unroll
  for (int hh = 0; hh < 8; ++hh)
    acc += (double)row[hh * 2 + 1] / (double)row[hh * 2];   // 2^40 scales cancel
  out[g] = (float)acc;
}

// ---------------- Plan B (ws too small): one block per group, no scratch ----
__device__ __forceinline__ float dot16_reduce(const float4 (&W)[16],
                                              const float4 xv, const int lane) {
  float p[16];
#pragma unroll
  for (int j = 0; j < 16; ++j)
    p[j] = W[j].x * xv.x + W[j].y * xv.y + W[j].z * xv.z + W[j].w * xv.w;
#pragma unroll
  for (int j = 0; j < 8; ++j) {
    float send = (lane & 1) ? p[j] : p[j + 8];
    float keep = (lane & 1) ? p[j + 8] : p[j];
    p[j] = keep + __shfl_xor(send, 1, 64);
  }
#pragma unroll
  for (int j = 0; j < 4; ++j) {
    float send = (lane & 2) ? p[j] : p[j + 4];
    float keep = (lane & 2) ? p[j + 4] : p[j];
    p[j] = keep + __shfl_xor(send, 2, 64);
  }
#pragma unroll
  for (int j = 0; j < 2; ++j) {
    float send = (lane & 4) ? p[j] : p[j + 2];
    float keep = (lane & 4) ? p[j + 2] : p[j];
    p[j] = keep + __shfl_xor(send, 4, 64);
  }
  {
    float send = (lane & 8) ? p[0] : p[1];
    float keep = (lane & 8) ? p[1] : p[0];
    p[0] = keep + __shfl_xor(send, 8, 64);
  }
  p[0] += __shfl_xor(p[0], 16, 64);
  p[0] += __shfl_xor(p[0], 32, 64);
  return p[0];
}

__device__ __forceinline__ int bitrev4(const int l4) {
  return ((l4 & 1) << 3) | ((l4 & 2) << 1) | ((l4 & 4) >> 1) | ((l4 & 8) >> 3);
}

__global__ __launch_bounds__(256) void group_scan(
    const float* __restrict__ x, const int* __restrict__ gid,
    const float* __restrict__ query, const float* __restrict__ w_in,
    const float* __restrict__ b_in, const float* __restrict__ w_out,
    const float* __restrict__ b_out, const float* __restrict__ w_lin,
    const float* __restrict__ b_lin, float* __restrict__ out, int n_items) {
  const int g = blockIdx.x;
  const int t = threadIdx.x;
  __shared__ float Wl[16 * EDIM];
  __shared__ float querys[EDIM], wls[EDIM], qs[EDIM], us[EDIM];
  __shared__ float qbias[8], ubias[8], csh;
  __shared__ float part[4][16], sums[16];

  querys[t] = query[t];
  wls[t] = w_lin[t];
  __syncthreads();
  {
    float acc = 0.f;
    const float4* wr = (const float4*)(w_in + (size_t)t * EDIM);
    for (int f4 = 0; f4 < EDIM / 4; ++f4) {
      float4 wv = wr[f4];
      int f = f4 * 4;
      acc += wv.x * querys[f] + wv.y * querys[f + 1] + wv.z * querys[f + 2] + wv.w * querys[f + 3];
    }
    qs[t] = acc + b_in[t];
  }
  {
    float acc = 0.f;
    for (int f = 0; f < EDIM; ++f) acc += wls[f] * w_out[(size_t)f * EDIM + t];
    us[t] = acc;
  }
  __syncthreads();
  for (int j = 0; j < 8; ++j) {
    float a = 0.f;
    for (int d = 0; d < 32; ++d)
      a += qs[j * 32 + d] * w_in[(size_t)(EDIM + j * 32 + d) * EDIM + t];
    Wl[j * EDIM + t] = a * INV_SQRT_D;
  }
  for (int j = 0; j < 8; ++j) {
    float a = 0.f;
    for (int d = 0; d < 32; ++d)
      a += us[j * 32 + d] * w_in[(size_t)(2 * EDIM + j * 32 + d) * EDIM + t];
    Wl[(8 + j) * EDIM + t] = a;
  }
  if (t < 8) {
    float qb = 0.f, ub = 0.f;
    for (int d = 0; d < 32; ++d) {
      qb += qs[t * 32 + d] * b_in[EDIM + t * 32 + d];
      ub += us[t * 32 + d] * b_in[2 * EDIM + t * 32 + d];
    }
    qbias[t] = qb * INV_SQRT_D;
    ubias[t] = ub;
  }
  if (t == 0) {
    float c = b_lin[0];
    for (int f = 0; f < EDIM; ++f) c += wls[f] * b_out[f];
    csh = c;
  }
  __syncthreads();

  const int lane = t & 63;
  const int wave = t >> 6;
  float4 W[16];
#pragma unroll
  for (int j = 0; j < 16; ++j)
    W[j] = *(const float4*)(Wl + j * EDIM + lane * 4);
  const int jv = bitrev4(lane & 15);
  const int h = jv & 7;
  const int isw = (jv >> 3) & 1;
  const float bias_s = qbias[h];
  const float bias_w = ubias[h];

  float accv = 0.f;
  const int nchunk = (n_items + 63) >> 6;
  for (int c = wave; c < nchunk; c += 4) {
    const int i0 = c << 6;
    const int ii = i0 + lane;
    const int gi = (ii < n_items) ? gid[ii] : -1;
    unsigned long long mk = __ballot(gi == g);
    while (mk) {
      const int bpos = __ffsll(mk) - 1;
      mk &= mk - 1;
      const int i = i0 + bpos;
      const float4 xv = *(const float4*)(x + (size_t)i * EDIM + lane * 4);
      const float p0 = dot16_reduce(W, xv, lane);
      const float tpair = __shfl_xor(p0, 1, 64);
      const float sv = (isw ? tpair : p0) + bias_s;
      const float wv = (isw ? p0 : tpair) + bias_w;
      const float e = __expf(sv);
      accv += isw ? e * wv : e;
    }
  }
  if (lane < 16) part[wave][h * 2 + isw] = accv;
  __syncthreads();
  if (t < 16) sums[t] = part[0][t] + part[1][t] + part[2][t] + part[3][t];
  __syncthreads();
  if (t == 0) {
    double acc = (double)csh;
    for (int hh = 0; hh < 8; ++hh)
      acc += (double)sums[2 * hh + 1] / (double)sums[2 * hh];
    out[g] = (float)acc;
  }
}

extern "C" void kernel_launch(void* const* d_in, const int* in_sizes, int n_in,
                              void* d_out, int out_size, void* d_ws, size_t ws_size,
                              hipStream_t stream) {
  const float* tree_preds = (const float*)d_in[0];
  const int* group_ids = (const int*)d_in[1];
  const float* query = (const float*)d_in[2];
  const float* w_in = (const float*)d_in[3];
  const float* b_in = (const float*)d_in[4];
  const float* w_out = (const float*)d_in[5];
  const float* b_out = (const float*)d_in[6];
  const float* w_lin = (const float*)d_in[7];
  const float* b_lin = (const float*)d_in[8];
  float* out = (float*)d_out;

  const int N = in_sizes[1];   // 131072
  const int G = out_size;      // 2048

  const size_t needA = (size_t)ZM_BYTE_OFF + (size_t)G * 16 * 8;
  if (ws_size >= needA) {
    float* ws = (float*)d_ws;
    unsigned short* wb = (unsigned short*)((char*)d_ws + WB_BYTE_OFF);
    unsigned long long* zm = (unsigned long long*)((char*)d_ws + ZM_BYTE_OFF);
    prep1<<<64, 256, 0, stream>>>(query, w_in, b_in, w_out, w_lin, ws, zm, G * 16);
    prep2<<<17, 256, 0, stream>>>(w_in, b_in, b_out, b_lin, w_lin, ws, wb);
    main_mfma<<<1024, 256, 0, stream>>>(tree_preds, group_ids, ws, wb, zm, N);
    finalize<<<(G + 255) / 256, 256, 0, stream>>>((const long long*)zm, ws, out, G);
  } else {
    group_scan<<<G, 256, 0, stream>>>(tree_preds, group_ids, query, w_in, b_in,
                                      w_out, b_out, w_lin, b_lin, out, N);
  }
}